// Round 1
// baseline (1225.719 us; speedup 1.0000x reference)
//
#include <hip/hip_runtime.h>
#include <math.h>

#define TOK 32768
#define CH  256
#define HIDN 1024
#define NE  8
#define BE  10240

typedef __attribute__((ext_vector_type(8))) short bf16x8;
typedef __attribute__((ext_vector_type(4))) float f32x4;

__device__ __forceinline__ unsigned short f2bf(float f) {
    unsigned u = __builtin_bit_cast(unsigned, f);
    unsigned r = 0x7FFFu + ((u >> 16) & 1u);
    return (unsigned short)((u + r) >> 16);
}

__global__ void k_init(int* cnt) {
    if (threadIdx.x < NE) cnt[threadIdx.x] = 0;
}

// Depthwise 7x7 conv + bias, NCHW in -> NHWC (token-major) out.
__global__ __launch_bounds__(256) void k_conv(const float* __restrict__ in,
                                              const float* __restrict__ kern,
                                              const float* __restrict__ bias,
                                              float* __restrict__ xc) {
    __shared__ float kw[49];
    int t = threadIdx.x;
    int id = blockIdx.x * 256 + t;
    int x = id & 31, y = (id >> 5) & 31, c = (id >> 10) & 255, n = id >> 18;
    if (t < 49) kw[t] = kern[c * 49 + t];
    __syncthreads();
    const float* ip = in + (size_t)(n * CH + c) * 1024;
    float s = bias[c];
#pragma unroll
    for (int dy = -3; dy <= 3; ++dy) {
        int yy = y + dy;
        if ((unsigned)yy < 32u) {
            const float* rp = ip + yy * 32;
#pragma unroll
            for (int dx = -3; dx <= 3; ++dx) {
                int xx = x + dx;
                if ((unsigned)xx < 32u) s += rp[xx] * kw[(dy + 3) * 7 + (dx + 3)];
            }
        }
    }
    int token = n * 1024 + y * 32 + x;
    xc[(size_t)token * CH + c] = s;
}

// LayerNorm + router (top-2 softmax) + capacity assignment. One wave per token.
__global__ __launch_bounds__(256) void k_ln_router(const float* __restrict__ xc,
                                                   const float* __restrict__ gamma,
                                                   const float* __restrict__ beta,
                                                   const float* __restrict__ rw,
                                                   unsigned short* __restrict__ xln,
                                                   int* __restrict__ cnt,
                                                   int* __restrict__ row_token,
                                                   int2* __restrict__ slots,
                                                   float2* __restrict__ gates) {
    int lane = threadIdx.x & 63;
    int wid  = threadIdx.x >> 6;
    int tok  = blockIdx.x * 4 + wid;

    const float4* xr = (const float4*)(xc + (size_t)tok * CH);
    float4 v = xr[lane];
    float s = v.x + v.y + v.z + v.w;
    float q = v.x * v.x + v.y * v.y + v.z * v.z + v.w * v.w;
#pragma unroll
    for (int m = 1; m < 64; m <<= 1) { s += __shfl_xor(s, m); q += __shfl_xor(q, m); }
    float mean = s * (1.0f / 256.0f);
    float var  = q * (1.0f / 256.0f) - mean * mean;
    float rstd = rsqrtf(var + 1e-6f);

    int c0 = lane * 4;
    float4 g4 = ((const float4*)gamma)[lane];
    float4 b4 = ((const float4*)beta)[lane];
    float xn[4];
    xn[0] = (v.x - mean) * rstd * g4.x + b4.x;
    xn[1] = (v.y - mean) * rstd * g4.y + b4.y;
    xn[2] = (v.z - mean) * rstd * g4.z + b4.z;
    xn[3] = (v.w - mean) * rstd * g4.w + b4.w;

    ushort4 pk;
    pk.x = f2bf(xn[0]); pk.y = f2bf(xn[1]); pk.z = f2bf(xn[2]); pk.w = f2bf(xn[3]);
    ((ushort4*)xln)[tok * 64 + lane] = pk;

    float p[8] = {0, 0, 0, 0, 0, 0, 0, 0};
#pragma unroll
    for (int j = 0; j < 4; ++j) {
        const float* rwp = rw + (size_t)(c0 + j) * 8;
        float xv = xn[j];
#pragma unroll
        for (int e = 0; e < 8; ++e) p[e] += xv * rwp[e];
    }
#pragma unroll
    for (int m = 1; m < 64; m <<= 1) {
#pragma unroll
        for (int e = 0; e < 8; ++e) p[e] += __shfl_xor(p[e], m);
    }

    if (lane == 0) {
        int e0 = 0; float l0 = p[0];
#pragma unroll
        for (int e = 1; e < 8; ++e) if (p[e] > l0) { l0 = p[e]; e0 = e; }
        int e1 = -1; float l1 = -3.4e38f;
#pragma unroll
        for (int e = 0; e < 8; ++e) if (e != e0 && p[e] > l1) { l1 = p[e]; e1 = e; }
        float tt = expf(l1 - l0);
        float w0 = 1.0f / (1.0f + tt);
        float w1 = 1.0f - w0;

        int pos0 = atomicAdd(cnt + e0, 1);
        int slot0 = (pos0 < BE) ? e0 * BE + pos0 : -1;
        if (slot0 >= 0) row_token[slot0] = tok;
        int pos1 = atomicAdd(cnt + e1, 1);
        int slot1 = (pos1 < BE) ? e1 * BE + pos1 : -1;
        if (slot1 >= 0) row_token[slot1] = tok;

        slots[tok] = make_int2(slot0, slot1);
        gates[tok] = make_float2(w0, w1);
    }
}

// Transpose R x S (f32) -> S x R (bf16), one matrix per blockIdx.z.
__global__ __launch_bounds__(256) void k_transpose(const float* __restrict__ in,
                                                   unsigned short* __restrict__ out,
                                                   int R, int S) {
    __shared__ float tile[32][33];
    size_t mb = (size_t)blockIdx.z * R * S;
    in += mb; out += mb;
    int tx = threadIdx.x & 31, ty = threadIdx.x >> 5;
    int sc = blockIdx.x * 32 + tx;
#pragma unroll
    for (int i = 0; i < 4; ++i) {
        int r = blockIdx.y * 32 + ty + i * 8;
        tile[ty + i * 8][tx] = in[(size_t)r * S + sc];
    }
    __syncthreads();
    int rc = blockIdx.y * 32 + tx;
#pragma unroll
    for (int i = 0; i < 4; ++i) {
        int sr = blockIdx.x * 32 + ty + i * 8;
        out[(size_t)sr * R + rc] = f2bf(tile[tx][ty + i * 8]);
    }
}

// Fused expert MLP: per block = 64 rows of one expert.
// Y[row] = gelu(x @ W1 + b1) @ W2 + b2, chunked over HID in 16 steps of 64.
__global__ __launch_bounds__(256) void k_mlp(const unsigned short* __restrict__ xln,
                                             const unsigned short* __restrict__ w1t,  // [E][HID][C]
                                             const unsigned short* __restrict__ w2t,  // [E][C][HID]
                                             const float* __restrict__ b1,
                                             const float* __restrict__ b2,
                                             const int* __restrict__ cnt,
                                             const int* __restrict__ row_token,
                                             float* __restrict__ Y) {
    int e = blockIdx.y;
    int nrows = min(cnt[e], BE);
    int row0 = blockIdx.x * 64;
    if (row0 >= nrows) return;

    __shared__ unsigned short Xs[64 * 256];  // XOR-swizzled, rows 512B
    __shared__ unsigned short Hs[64 * 64];   // XOR-swizzled, rows 128B
    __shared__ int tokl[64];

    int t = threadIdx.x;
    if (t < 64) {
        int r = row0 + t;
        tokl[t] = (r < nrows) ? row_token[e * BE + r] : 0;
    }
    __syncthreads();

    {   // stage Xs: 64 rows x 512B, 4 threads/row, 16B chunks, chunk ^= (row&7)
        int r = t >> 2, qq = t & 3;
        const char* src = (const char*)(xln + (size_t)tokl[r] * 256);
        char* dstrow = (char*)Xs + r * 512;
#pragma unroll
        for (int i = 0; i < 8; ++i) {
            int cb = qq * 16 + i * 64;
            int chunk = cb >> 4;
            *(int4*)(dstrow + ((chunk ^ (r & 7)) << 4)) = *(const int4*)(src + cb);
        }
    }
    __syncthreads();

    int lane = t & 63, w = t >> 6;
    int l15 = lane & 15, l4 = lane >> 4;
    const unsigned short* w1e = w1t + (size_t)e * HIDN * 256;
    const unsigned short* w2e = w2t + (size_t)e * 256 * HIDN;

    f32x4 yacc[4][4];
#pragma unroll
    for (int m = 0; m < 4; ++m)
#pragma unroll
        for (int nf = 0; nf < 4; ++nf) yacc[m][nf] = f32x4{0.f, 0.f, 0.f, 0.f};

    for (int hc = 0; hc < 16; ++hc) {
        // ---- phase A: Hc[0:64][w*16 .. w*16+16) = Xs @ W1 chunk
        f32x4 hacc[4];
#pragma unroll
        for (int m = 0; m < 4; ++m) hacc[m] = f32x4{0.f, 0.f, 0.f, 0.f};
        int nA = hc * 64 + w * 16 + l15;  // W1t row (hid index)
#pragma unroll
        for (int ks = 0; ks < 8; ++ks) {
            bf16x8 bfrag = *(const bf16x8*)(w1e + (size_t)nA * 256 + ks * 32 + l4 * 8);
#pragma unroll
            for (int m = 0; m < 4; ++m) {
                int r = m * 16 + l15;
                int chunk = ks * 4 + l4;
                bf16x8 afrag = *(const bf16x8*)((const char*)Xs + r * 512 + ((chunk ^ (r & 7)) << 4));
                hacc[m] = __builtin_amdgcn_mfma_f32_16x16x32_bf16(afrag, bfrag, hacc[m], 0, 0, 0);
            }
        }
        float bb = b1[e * HIDN + hc * 64 + w * 16 + l15];
#pragma unroll
        for (int m = 0; m < 4; ++m) {
#pragma unroll
            for (int j = 0; j < 4; ++j) {
                int r = m * 16 + l4 * 4 + j;
                float vv = hacc[m][j] + bb;
                float gl = 0.5f * vv * (1.0f + erff(vv * 0.70710678f));
                int colb = (w * 16 + l15) * 2;
                int chunk = colb >> 4;
                int sw = ((chunk ^ (r & 7)) << 4) | (colb & 15);
                *(short*)((char*)Hs + r * 128 + sw) = (short)f2bf(gl);
            }
        }
        __syncthreads();
        // ---- phase B: Y[0:64][w*64 .. w*64+64) += Hs @ W2 chunk
#pragma unroll
        for (int ks = 0; ks < 2; ++ks) {
            bf16x8 aH[4];
#pragma unroll
            for (int m = 0; m < 4; ++m) {
                int r = m * 16 + l15;
                int chunk = ks * 4 + l4;
                aH[m] = *(const bf16x8*)((const char*)Hs + r * 128 + ((chunk ^ (r & 7)) << 4));
            }
#pragma unroll
            for (int nf = 0; nf < 4; ++nf) {
                int ncol = w * 64 + nf * 16 + l15;
                bf16x8 bW = *(const bf16x8*)(w2e + (size_t)ncol * HIDN + hc * 64 + ks * 32 + l4 * 8);
#pragma unroll
                for (int m = 0; m < 4; ++m)
                    yacc[m][nf] = __builtin_amdgcn_mfma_f32_16x16x32_bf16(aH[m], bW, yacc[m][nf], 0, 0, 0);
            }
        }
        __syncthreads();
    }
#pragma unroll
    for (int nf = 0; nf < 4; ++nf) {
        int col = w * 64 + nf * 16 + l15;
        float bb2 = b2[e * 256 + col];
#pragma unroll
        for (int m = 0; m < 4; ++m)
#pragma unroll
            for (int j = 0; j < 4; ++j) {
                int r = row0 + m * 16 + l4 * 4 + j;
                Y[((size_t)e * BE + r) * 256 + col] = yacc[m][nf][j] + bb2;
            }
    }
}

// Gather expert outputs, gate, add residual, write NCHW. One block per (n,y) row.
__global__ __launch_bounds__(256) void k_gather(const float* __restrict__ input,
                                                const float* __restrict__ Y,
                                                const int2* __restrict__ slots,
                                                const float2* __restrict__ gates,
                                                const float* __restrict__ ls,
                                                float* __restrict__ out) {
    __shared__ float acc[32][257];
    int t = threadIdx.x;
    int n = blockIdx.x >> 5, y = blockIdx.x & 31;

    {   // step 1: per-token gated contribution into LDS [token][c]
        int tl = t & 31, chunk = t >> 5;
        int tok = n * 1024 + y * 32 + tl;
        int2  sl = slots[tok];
        float2 gw = gates[tok];
        int c0 = chunk * 32;
#pragma unroll
        for (int i = 0; i < 8; ++i) {
            int c = c0 + i * 4;
            float sx = 0.f, sy = 0.f, sz = 0.f, sw = 0.f;
            if (sl.x >= 0) {
                float4 yv = *(const float4*)(Y + (size_t)sl.x * 256 + c);
                sx += gw.x * yv.x; sy += gw.x * yv.y; sz += gw.x * yv.z; sw += gw.x * yv.w;
            }
            if (sl.y >= 0) {
                float4 yv = *(const float4*)(Y + (size_t)sl.y * 256 + c);
                sx += gw.y * yv.x; sy += gw.y * yv.y; sz += gw.y * yv.z; sw += gw.y * yv.w;
            }
            acc[tl][c] = sx; acc[tl][c + 1] = sy; acc[tl][c + 2] = sz; acc[tl][c + 3] = sw;
        }
    }
    __syncthreads();
    {   // step 2: out[n,c,y,x] = input + ls[c] * acc[x][c], coalesced
        int x = t & 31, c8 = t >> 5;
        size_t base = (size_t)n * 256 * 1024 + (size_t)y * 32 + x;
#pragma unroll
        for (int p = 0; p < 32; ++p) {
            int c = p * 8 + c8;
            size_t id = base + (size_t)c * 1024;
            out[id] = input[id] + ls[c] * acc[x][c];
        }
    }
}

extern "C" void kernel_launch(void* const* d_in, const int* in_sizes, int n_in,
                              void* d_out, int out_size, void* d_ws, size_t ws_size,
                              hipStream_t stream) {
    const float* input = (const float*)d_in[0];
    const float* dwk   = (const float*)d_in[1];
    const float* dwb   = (const float*)d_in[2];
    const float* gamma = (const float*)d_in[3];
    const float* beta  = (const float*)d_in[4];
    const float* rw    = (const float*)d_in[5];
    const float* w1    = (const float*)d_in[6];
    const float* b1    = (const float*)d_in[7];
    const float* w2    = (const float*)d_in[8];
    const float* b2    = (const float*)d_in[9];
    const float* ls    = (const float*)d_in[10];

    char* ws = (char*)d_ws;
    // Y (80MB) aliases xc (32MB): xc is dead before k_mlp writes Y.
    float*          Yb   = (float*)ws;
    float*          xc   = (float*)ws;
    unsigned short* xln  = (unsigned short*)(ws + 83886080);   // 16MB
    unsigned short* w1t  = (unsigned short*)(ws + 100663296);  // 4MB
    unsigned short* w2t  = (unsigned short*)(ws + 104857600);  // 4MB
    int*            rtok = (int*)(ws + 109051904);             // 320KB
    int2*           slots = (int2*)(ws + 109379584);           // 256KB
    float2*         gates = (float2*)(ws + 109641728);         // 256KB
    int*            cnt  = (int*)(ws + 109903872);

    k_init<<<1, 64, 0, stream>>>(cnt);
    k_conv<<<32768, 256, 0, stream>>>(input, dwk, dwb, xc);
    k_ln_router<<<8192, 256, 0, stream>>>(xc, gamma, beta, rw, xln, cnt, rtok, slots, gates);
    k_transpose<<<dim3(32, 8, 8), 256, 0, stream>>>(w1, w1t, 256, 1024);  // w1t[e][h][c]
    k_transpose<<<dim3(8, 32, 8), 256, 0, stream>>>(w2, w2t, 1024, 256);  // w2t[e][c][h]
    k_mlp<<<dim3(160, 8), 256, 0, stream>>>(xln, w1t, w2t, b1, b2, cnt, rtok, Yb);
    k_gather<<<1024, 256, 0, stream>>>(input, Yb, slots, gates, ls, (float*)d_out);
}

// Round 2
// 506.110 us; speedup vs baseline: 2.4218x; 2.4218x over previous
//
#include <hip/hip_runtime.h>
#include <math.h>

#define TOK 32768
#define CH  256
#define HIDN 1024
#define NE  8
#define BE  10240
#define CNT_STRIDE 64  // ints between expert counters (256B, separate cache lines)

typedef __attribute__((ext_vector_type(8))) short bf16x8;
typedef __attribute__((ext_vector_type(4))) float f32x4;

__device__ __forceinline__ unsigned short f2bf(float f) {
    unsigned u = __builtin_bit_cast(unsigned, f);
    unsigned r = 0x7FFFu + ((u >> 16) & 1u);
    return (unsigned short)((u + r) >> 16);
}

__global__ void k_init(int* cnt) {
    cnt[threadIdx.x] = 0;
}

// Depthwise 7x7 conv + bias, NCHW in -> NHWC (token-major) out.
__global__ __launch_bounds__(256) void k_conv(const float* __restrict__ in,
                                              const float* __restrict__ kern,
                                              const float* __restrict__ bias,
                                              float* __restrict__ xc) {
    __shared__ float kw[49];
    int t = threadIdx.x;
    int id = blockIdx.x * 256 + t;
    int x = id & 31, y = (id >> 5) & 31, c = (id >> 10) & 255, n = id >> 18;
    if (t < 49) kw[t] = kern[c * 49 + t];
    __syncthreads();
    const float* ip = in + (size_t)(n * CH + c) * 1024;
    float s = bias[c];
#pragma unroll
    for (int dy = -3; dy <= 3; ++dy) {
        int yy = y + dy;
        if ((unsigned)yy < 32u) {
            const float* rp = ip + yy * 32;
#pragma unroll
            for (int dx = -3; dx <= 3; ++dx) {
                int xx = x + dx;
                if ((unsigned)xx < 32u) s += rp[xx] * kw[(dy + 3) * 7 + (dx + 3)];
            }
        }
    }
    int token = n * 1024 + y * 32 + x;
    xc[(size_t)token * CH + c] = s;
}

// LayerNorm + router top-2 (no atomics). One wave per token.
__global__ __launch_bounds__(256) void k_ln_router(const float* __restrict__ xc,
                                                   const float* __restrict__ gamma,
                                                   const float* __restrict__ beta,
                                                   const float* __restrict__ rw,
                                                   unsigned short* __restrict__ xln,
                                                   int* __restrict__ e01,
                                                   float2* __restrict__ gates) {
    int lane = threadIdx.x & 63;
    int wid  = threadIdx.x >> 6;
    int tok  = blockIdx.x * 4 + wid;

    const float4* xr = (const float4*)(xc + (size_t)tok * CH);
    float4 v = xr[lane];
    float s = v.x + v.y + v.z + v.w;
    float q = v.x * v.x + v.y * v.y + v.z * v.z + v.w * v.w;
#pragma unroll
    for (int m = 1; m < 64; m <<= 1) { s += __shfl_xor(s, m); q += __shfl_xor(q, m); }
    float mean = s * (1.0f / 256.0f);
    float var  = q * (1.0f / 256.0f) - mean * mean;
    float rstd = rsqrtf(var + 1e-6f);

    float4 g4 = ((const float4*)gamma)[lane];
    float4 b4 = ((const float4*)beta)[lane];
    float xn[4];
    xn[0] = (v.x - mean) * rstd * g4.x + b4.x;
    xn[1] = (v.y - mean) * rstd * g4.y + b4.y;
    xn[2] = (v.z - mean) * rstd * g4.z + b4.z;
    xn[3] = (v.w - mean) * rstd * g4.w + b4.w;

    ushort4 pk;
    pk.x = f2bf(xn[0]); pk.y = f2bf(xn[1]); pk.z = f2bf(xn[2]); pk.w = f2bf(xn[3]);
    ((ushort4*)xln)[tok * 64 + lane] = pk;

    float p[8] = {0, 0, 0, 0, 0, 0, 0, 0};
    int c0 = lane * 4;
#pragma unroll
    for (int j = 0; j < 4; ++j) {
        const float* rwp = rw + (size_t)(c0 + j) * 8;
        float xv = xn[j];
#pragma unroll
        for (int e = 0; e < 8; ++e) p[e] += xv * rwp[e];
    }
#pragma unroll
    for (int m = 1; m < 64; m <<= 1) {
#pragma unroll
        for (int e = 0; e < 8; ++e) p[e] += __shfl_xor(p[e], m);
    }

    if (lane == 0) {
        int e0 = 0; float l0 = p[0];
#pragma unroll
        for (int e = 1; e < 8; ++e) if (p[e] > l0) { l0 = p[e]; e0 = e; }
        int e1 = -1; float l1 = -3.4e38f;
#pragma unroll
        for (int e = 0; e < 8; ++e) if (e != e0 && p[e] > l1) { l1 = p[e]; e1 = e; }
        float tt = expf(l1 - l0);
        float w0 = 1.0f / (1.0f + tt);
        e01[tok] = e0 | (e1 << 8);
        gates[tok] = make_float2(w0, 1.0f - w0);
    }
}

// Hierarchical capacity assignment: LDS counts + one global atomic per expert per block.
__global__ __launch_bounds__(256) void k_assign(const int* __restrict__ e01,
                                                int* __restrict__ cnt,
                                                int* __restrict__ row_token,
                                                int2* __restrict__ slots) {
    __shared__ int lcnt[8];
    __shared__ int base[8];
    int t = threadIdx.x;
    if (t < 8) lcnt[t] = 0;
    __syncthreads();
    int tok = blockIdx.x * 256 + t;
    int ee = e01[tok];
    int e0 = ee & 255, e1 = (ee >> 8) & 255;
    int lp0 = atomicAdd(&lcnt[e0], 1);
    int lp1 = atomicAdd(&lcnt[e1], 1);
    __syncthreads();
    if (t < 8) base[t] = atomicAdd(cnt + t * CNT_STRIDE, lcnt[t]);
    __syncthreads();
    int pos0 = base[e0] + lp0;
    int pos1 = base[e1] + lp1;
    int slot0 = (pos0 < BE) ? e0 * BE + pos0 : -1;
    int slot1 = (pos1 < BE) ? e1 * BE + pos1 : -1;
    if (slot0 >= 0) row_token[slot0] = tok;
    if (slot1 >= 0) row_token[slot1] = tok;
    slots[tok] = make_int2(slot0, slot1);
}

// Transpose R x S (f32) -> S x R (bf16), one matrix per blockIdx.z.
__global__ __launch_bounds__(256) void k_transpose(const float* __restrict__ in,
                                                   unsigned short* __restrict__ out,
                                                   int R, int S) {
    __shared__ float tile[32][33];
    size_t mb = (size_t)blockIdx.z * R * S;
    in += mb; out += mb;
    int tx = threadIdx.x & 31, ty = threadIdx.x >> 5;
    int sc = blockIdx.x * 32 + tx;
#pragma unroll
    for (int i = 0; i < 4; ++i) {
        int r = blockIdx.y * 32 + ty + i * 8;
        tile[ty + i * 8][tx] = in[(size_t)r * S + sc];
    }
    __syncthreads();
    int rc = blockIdx.y * 32 + tx;
#pragma unroll
    for (int i = 0; i < 4; ++i) {
        int sr = blockIdx.x * 32 + ty + i * 8;
        out[(size_t)sr * R + rc] = f2bf(tile[tx][ty + i * 8]);
    }
}

// Fused expert MLP: per block = 64 rows of one expert.
// Y[row] = gelu(x @ W1 + b1) @ W2 + b2, chunked over HID in 16 steps of 64.
__global__ __launch_bounds__(256) void k_mlp(const unsigned short* __restrict__ xln,
                                             const unsigned short* __restrict__ w1t,  // [E][HID][C]
                                             const unsigned short* __restrict__ w2t,  // [E][C][HID]
                                             const float* __restrict__ b1,
                                             const float* __restrict__ b2,
                                             const int* __restrict__ cnt,
                                             const int* __restrict__ row_token,
                                             float* __restrict__ Y) {
    int e = blockIdx.y;
    int nrows = min(cnt[e * CNT_STRIDE], BE);
    int row0 = blockIdx.x * 64;
    if (row0 >= nrows) return;

    __shared__ unsigned short Xs[64 * 256];  // XOR-swizzled, rows 512B
    __shared__ unsigned short Hs[64 * 64];   // XOR-swizzled, rows 128B
    __shared__ int tokl[64];

    int t = threadIdx.x;
    if (t < 64) {
        int r = row0 + t;
        tokl[t] = (r < nrows) ? row_token[e * BE + r] : 0;
    }
    __syncthreads();

    {   // stage Xs: 64 rows x 512B, 4 threads/row, 16B chunks, chunk ^= (row&7)
        int r = t >> 2, qq = t & 3;
        const char* src = (const char*)(xln + (size_t)tokl[r] * 256);
        char* dstrow = (char*)Xs + r * 512;
#pragma unroll
        for (int i = 0; i < 8; ++i) {
            int cb = qq * 16 + i * 64;
            int chunk = cb >> 4;
            *(int4*)(dstrow + ((chunk ^ (r & 7)) << 4)) = *(const int4*)(src + cb);
        }
    }
    __syncthreads();

    int lane = t & 63, w = t >> 6;
    int l15 = lane & 15, l4 = lane >> 4;
    const unsigned short* w1e = w1t + (size_t)e * HIDN * 256;
    const unsigned short* w2e = w2t + (size_t)e * 256 * HIDN;

    f32x4 yacc[4][4];
#pragma unroll
    for (int m = 0; m < 4; ++m)
#pragma unroll
        for (int nf = 0; nf < 4; ++nf) yacc[m][nf] = f32x4{0.f, 0.f, 0.f, 0.f};

    for (int hc = 0; hc < 16; ++hc) {
        // ---- phase A: Hc[0:64][w*16 .. w*16+16) = Xs @ W1 chunk
        f32x4 hacc[4];
#pragma unroll
        for (int m = 0; m < 4; ++m) hacc[m] = f32x4{0.f, 0.f, 0.f, 0.f};
        int nA = hc * 64 + w * 16 + l15;  // W1t row (hid index)
#pragma unroll
        for (int ks = 0; ks < 8; ++ks) {
            bf16x8 bfrag = *(const bf16x8*)(w1e + (size_t)nA * 256 + ks * 32 + l4 * 8);
#pragma unroll
            for (int m = 0; m < 4; ++m) {
                int r = m * 16 + l15;
                int chunk = ks * 4 + l4;
                bf16x8 afrag = *(const bf16x8*)((const char*)Xs + r * 512 + ((chunk ^ (r & 7)) << 4));
                hacc[m] = __builtin_amdgcn_mfma_f32_16x16x32_bf16(afrag, bfrag, hacc[m], 0, 0, 0);
            }
        }
        float bb = b1[e * HIDN + hc * 64 + w * 16 + l15];
#pragma unroll
        for (int m = 0; m < 4; ++m) {
#pragma unroll
            for (int j = 0; j < 4; ++j) {
                int r = m * 16 + l4 * 4 + j;
                float vv = hacc[m][j] + bb;
                float gl = 0.5f * vv * (1.0f + erff(vv * 0.70710678f));
                int colb = (w * 16 + l15) * 2;
                int chunk = colb >> 4;
                int sw = ((chunk ^ (r & 7)) << 4) | (colb & 15);
                *(short*)((char*)Hs + r * 128 + sw) = (short)f2bf(gl);
            }
        }
        __syncthreads();
        // ---- phase B: Y[0:64][w*64 .. w*64+64) += Hs @ W2 chunk
#pragma unroll
        for (int ks = 0; ks < 2; ++ks) {
            bf16x8 aH[4];
#pragma unroll
            for (int m = 0; m < 4; ++m) {
                int r = m * 16 + l15;
                int chunk = ks * 4 + l4;
                aH[m] = *(const bf16x8*)((const char*)Hs + r * 128 + ((chunk ^ (r & 7)) << 4));
            }
#pragma unroll
            for (int nf = 0; nf < 4; ++nf) {
                int ncol = w * 64 + nf * 16 + l15;
                bf16x8 bW = *(const bf16x8*)(w2e + (size_t)ncol * HIDN + hc * 64 + ks * 32 + l4 * 8);
#pragma unroll
                for (int m = 0; m < 4; ++m)
                    yacc[m][nf] = __builtin_amdgcn_mfma_f32_16x16x32_bf16(aH[m], bW, yacc[m][nf], 0, 0, 0);
            }
        }
        __syncthreads();
    }
#pragma unroll
    for (int nf = 0; nf < 4; ++nf) {
        int col = w * 64 + nf * 16 + l15;
        float bb2 = b2[e * 256 + col];
#pragma unroll
        for (int m = 0; m < 4; ++m)
#pragma unroll
            for (int j = 0; j < 4; ++j) {
                int r = row0 + m * 16 + l4 * 4 + j;
                Y[((size_t)e * BE + r) * 256 + col] = yacc[m][nf][j] + bb2;
            }
    }
}

// Gather expert outputs, gate, add residual, write NCHW. One block per (n,y) row.
__global__ __launch_bounds__(256) void k_gather(const float* __restrict__ input,
                                                const float* __restrict__ Y,
                                                const int2* __restrict__ slots,
                                                const float2* __restrict__ gates,
                                                const float* __restrict__ ls,
                                                float* __restrict__ out) {
    __shared__ float acc[32][257];
    int t = threadIdx.x;
    int n = blockIdx.x >> 5, y = blockIdx.x & 31;

    {   // step 1: per-token gated contribution into LDS [token][c]
        int tl = t & 31, chunk = t >> 5;
        int tok = n * 1024 + y * 32 + tl;
        int2  sl = slots[tok];
        float2 gw = gates[tok];
        int c0 = chunk * 32;
#pragma unroll
        for (int i = 0; i < 8; ++i) {
            int c = c0 + i * 4;
            float sx = 0.f, sy = 0.f, sz = 0.f, sw = 0.f;
            if (sl.x >= 0) {
                float4 yv = *(const float4*)(Y + (size_t)sl.x * 256 + c);
                sx += gw.x * yv.x; sy += gw.x * yv.y; sz += gw.x * yv.z; sw += gw.x * yv.w;
            }
            if (sl.y >= 0) {
                float4 yv = *(const float4*)(Y + (size_t)sl.y * 256 + c);
                sx += gw.y * yv.x; sy += gw.y * yv.y; sz += gw.y * yv.z; sw += gw.y * yv.w;
            }
            acc[tl][c] = sx; acc[tl][c + 1] = sy; acc[tl][c + 2] = sz; acc[tl][c + 3] = sw;
        }
    }
    __syncthreads();
    {   // step 2: out[n,c,y,x] = input + ls[c] * acc[x][c], coalesced
        int x = t & 31, c8 = t >> 5;
        size_t base = (size_t)n * 256 * 1024 + (size_t)y * 32 + x;
#pragma unroll
        for (int p = 0; p < 32; ++p) {
            int c = p * 8 + c8;
            size_t id = base + (size_t)c * 1024;
            out[id] = input[id] + ls[c] * acc[x][c];
        }
    }
}

extern "C" void kernel_launch(void* const* d_in, const int* in_sizes, int n_in,
                              void* d_out, int out_size, void* d_ws, size_t ws_size,
                              hipStream_t stream) {
    const float* input = (const float*)d_in[0];
    const float* dwk   = (const float*)d_in[1];
    const float* dwb   = (const float*)d_in[2];
    const float* gamma = (const float*)d_in[3];
    const float* beta  = (const float*)d_in[4];
    const float* rw    = (const float*)d_in[5];
    const float* w1    = (const float*)d_in[6];
    const float* b1    = (const float*)d_in[7];
    const float* w2    = (const float*)d_in[8];
    const float* b2    = (const float*)d_in[9];
    const float* ls    = (const float*)d_in[10];

    char* ws = (char*)d_ws;
    // Y (80MB) aliases xc (32MB): xc is dead before k_mlp writes Y.
    float*          Yb   = (float*)ws;
    float*          xc   = (float*)ws;
    unsigned short* xln  = (unsigned short*)(ws + 83886080);   // 16MB
    unsigned short* w1t  = (unsigned short*)(ws + 100663296);  // 4MB
    unsigned short* w2t  = (unsigned short*)(ws + 104857600);  // 4MB
    int*            rtok = (int*)(ws + 109051904);             // 320KB
    int2*           slots = (int2*)(ws + 109379584);           // 256KB
    float2*         gates = (float2*)(ws + 109641728);         // 256KB
    int*            e01  = (int*)(ws + 109903872);             // 128KB
    int*            cnt  = (int*)(ws + 110035968);             // 8*64 ints

    k_init<<<1, NE * CNT_STRIDE, 0, stream>>>(cnt);
    k_conv<<<32768, 256, 0, stream>>>(input, dwk, dwb, xc);
    k_ln_router<<<8192, 256, 0, stream>>>(xc, gamma, beta, rw, xln, e01, gates);
    k_assign<<<128, 256, 0, stream>>>(e01, cnt, rtok, slots);
    k_transpose<<<dim3(32, 8, 8), 256, 0, stream>>>(w1, w1t, 256, 1024);  // w1t[e][h][c]
    k_transpose<<<dim3(8, 32, 8), 256, 0, stream>>>(w2, w2t, 1024, 256);  // w2t[e][c][h]
    k_mlp<<<dim3(160, 8), 256, 0, stream>>>(xln, w1t, w2t, b1, b2, cnt, rtok, Yb);
    k_gather<<<1024, 256, 0, stream>>>(input, Yb, slots, gates, ls, (float*)d_out);
}

// Round 3
// 491.222 us; speedup vs baseline: 2.4952x; 1.0303x over previous
//
#include <hip/hip_runtime.h>
#include <math.h>

#define TOK 32768
#define CH  256
#define HIDN 1024
#define NE  8
#define BE  10240
#define CNT_STRIDE 64  // ints between expert counters (256B, separate cache lines)

typedef __attribute__((ext_vector_type(8))) short bf16x8;
typedef __attribute__((ext_vector_type(4))) float f32x4;

__device__ __forceinline__ unsigned short f2bf(float f) {
    unsigned u = __builtin_bit_cast(unsigned, f);
    unsigned r = 0x7FFFu + ((u >> 16) & 1u);
    return (unsigned short)((u + r) >> 16);
}
__device__ __forceinline__ float bf2f(unsigned short u) {
    return __builtin_bit_cast(float, (unsigned)u << 16);
}

__global__ void k_init(int* cnt) {
    cnt[threadIdx.x] = 0;
}

// Depthwise 7x7 conv + bias, NCHW in -> NHWC (token-major) out.
__global__ __launch_bounds__(256) void k_conv(const float* __restrict__ in,
                                              const float* __restrict__ kern,
                                              const float* __restrict__ bias,
                                              float* __restrict__ xc) {
    __shared__ float kw[49];
    int t = threadIdx.x;
    int id = blockIdx.x * 256 + t;
    int x = id & 31, y = (id >> 5) & 31, c = (id >> 10) & 255, n = id >> 18;
    if (t < 49) kw[t] = kern[c * 49 + t];
    __syncthreads();
    const float* ip = in + (size_t)(n * CH + c) * 1024;
    float s = bias[c];
#pragma unroll
    for (int dy = -3; dy <= 3; ++dy) {
        int yy = y + dy;
        if ((unsigned)yy < 32u) {
            const float* rp = ip + yy * 32;
#pragma unroll
            for (int dx = -3; dx <= 3; ++dx) {
                int xx = x + dx;
                if ((unsigned)xx < 32u) s += rp[xx] * kw[(dy + 3) * 7 + (dx + 3)];
            }
        }
    }
    int token = n * 1024 + y * 32 + x;
    xc[(size_t)token * CH + c] = s;
}

// LayerNorm + router top-2 (no atomics). One wave per token.
__global__ __launch_bounds__(256) void k_ln_router(const float* __restrict__ xc,
                                                   const float* __restrict__ gamma,
                                                   const float* __restrict__ beta,
                                                   const float* __restrict__ rw,
                                                   unsigned short* __restrict__ xln,
                                                   int* __restrict__ e01,
                                                   float2* __restrict__ gates) {
    int lane = threadIdx.x & 63;
    int wid  = threadIdx.x >> 6;
    int tok  = blockIdx.x * 4 + wid;

    const float4* xr = (const float4*)(xc + (size_t)tok * CH);
    float4 v = xr[lane];
    float s = v.x + v.y + v.z + v.w;
    float q = v.x * v.x + v.y * v.y + v.z * v.z + v.w * v.w;
#pragma unroll
    for (int m = 1; m < 64; m <<= 1) { s += __shfl_xor(s, m); q += __shfl_xor(q, m); }
    float mean = s * (1.0f / 256.0f);
    float var  = q * (1.0f / 256.0f) - mean * mean;
    float rstd = rsqrtf(var + 1e-6f);

    float4 g4 = ((const float4*)gamma)[lane];
    float4 b4 = ((const float4*)beta)[lane];
    float xn[4];
    xn[0] = (v.x - mean) * rstd * g4.x + b4.x;
    xn[1] = (v.y - mean) * rstd * g4.y + b4.y;
    xn[2] = (v.z - mean) * rstd * g4.z + b4.z;
    xn[3] = (v.w - mean) * rstd * g4.w + b4.w;

    ushort4 pk;
    pk.x = f2bf(xn[0]); pk.y = f2bf(xn[1]); pk.z = f2bf(xn[2]); pk.w = f2bf(xn[3]);
    ((ushort4*)xln)[tok * 64 + lane] = pk;

    float p[8] = {0, 0, 0, 0, 0, 0, 0, 0};
    int c0 = lane * 4;
#pragma unroll
    for (int j = 0; j < 4; ++j) {
        const float* rwp = rw + (size_t)(c0 + j) * 8;
        float xv = xn[j];
#pragma unroll
        for (int e = 0; e < 8; ++e) p[e] += xv * rwp[e];
    }
#pragma unroll
    for (int m = 1; m < 64; m <<= 1) {
#pragma unroll
        for (int e = 0; e < 8; ++e) p[e] += __shfl_xor(p[e], m);
    }

    if (lane == 0) {
        int e0 = 0; float l0 = p[0];
#pragma unroll
        for (int e = 1; e < 8; ++e) if (p[e] > l0) { l0 = p[e]; e0 = e; }
        int e1 = -1; float l1 = -3.4e38f;
#pragma unroll
        for (int e = 0; e < 8; ++e) if (e != e0 && p[e] > l1) { l1 = p[e]; e1 = e; }
        float tt = expf(l1 - l0);
        float w0 = 1.0f / (1.0f + tt);
        e01[tok] = e0 | (e1 << 8);
        gates[tok] = make_float2(w0, 1.0f - w0);
    }
}

// Hierarchical capacity assignment: LDS counts + one global atomic per expert per block.
__global__ __launch_bounds__(256) void k_assign(const int* __restrict__ e01,
                                                int* __restrict__ cnt,
                                                int* __restrict__ row_token,
                                                int2* __restrict__ slots) {
    __shared__ int lcnt[8];
    __shared__ int base[8];
    int t = threadIdx.x;
    if (t < 8) lcnt[t] = 0;
    __syncthreads();
    int tok = blockIdx.x * 256 + t;
    int ee = e01[tok];
    int e0 = ee & 255, e1 = (ee >> 8) & 255;
    int lp0 = atomicAdd(&lcnt[e0], 1);
    int lp1 = atomicAdd(&lcnt[e1], 1);
    __syncthreads();
    if (t < 8) base[t] = atomicAdd(cnt + t * CNT_STRIDE, lcnt[t]);
    __syncthreads();
    int pos0 = base[e0] + lp0;
    int pos1 = base[e1] + lp1;
    int slot0 = (pos0 < BE) ? e0 * BE + pos0 : -1;
    int slot1 = (pos1 < BE) ? e1 * BE + pos1 : -1;
    if (slot0 >= 0) row_token[slot0] = tok;
    if (slot1 >= 0) row_token[slot1] = tok;
    slots[tok] = make_int2(slot0, slot1);
}

// Transpose R x S (f32) -> S x R (bf16), one matrix per blockIdx.z.
__global__ __launch_bounds__(256) void k_transpose(const float* __restrict__ in,
                                                   unsigned short* __restrict__ out,
                                                   int R, int S) {
    __shared__ float tile[32][33];
    size_t mb = (size_t)blockIdx.z * R * S;
    in += mb; out += mb;
    int tx = threadIdx.x & 31, ty = threadIdx.x >> 5;
    int sc = blockIdx.x * 32 + tx;
#pragma unroll
    for (int i = 0; i < 4; ++i) {
        int r = blockIdx.y * 32 + ty + i * 8;
        tile[ty + i * 8][tx] = in[(size_t)r * S + sc];
    }
    __syncthreads();
    int rc = blockIdx.y * 32 + tx;
#pragma unroll
    for (int i = 0; i < 4; ++i) {
        int sr = blockIdx.x * 32 + ty + i * 8;
        out[(size_t)sr * R + rc] = f2bf(tile[tx][ty + i * 8]);
    }
}

// Fused expert MLP: per block = 64 rows of one expert, expert = bid&7 (XCD-pinned).
// hid processed in 8 chunks of 128. Y out in bf16.
__global__ __launch_bounds__(256, 3) void k_mlp(const unsigned short* __restrict__ xln,
                                                const unsigned short* __restrict__ w1t,  // [E][HID][C]
                                                const unsigned short* __restrict__ w2t,  // [E][C][HID]
                                                const float* __restrict__ b1,
                                                const float* __restrict__ b2,
                                                const int* __restrict__ cnt,
                                                const int* __restrict__ row_token,
                                                unsigned short* __restrict__ Y) {
    int bid = blockIdx.x;
    int e = bid & 7;                 // XCD pinning: all blocks of expert e on XCD e
    int row0 = (bid >> 3) * 64;
    int nrows = min(cnt[e * CNT_STRIDE], BE);
    if (row0 >= nrows) return;

    __shared__ unsigned short Xs[64 * 256];  // rows 512B, 16B-chunk ^ (r&31)
    __shared__ unsigned short Hs[64 * 128];  // rows 256B, 16B-chunk ^ (r&15)
    __shared__ int tokl[64];

    int t = threadIdx.x;
    if (t < 64) {
        int r = row0 + t;
        tokl[t] = (r < nrows) ? row_token[e * BE + r] : 0;
    }
    __syncthreads();

    {   // stage Xs: 4 threads/row, 16B chunks, chunk ^= (r&31)
        int r = t >> 2, qq = t & 3;
        const char* src = (const char*)(xln + (size_t)tokl[r] * 256);
        char* dstrow = (char*)Xs + r * 512;
#pragma unroll
        for (int i = 0; i < 8; ++i) {
            int chunk = qq + i * 4;
            *(int4*)(dstrow + ((chunk ^ (r & 31)) << 4)) = *(const int4*)(src + chunk * 16);
        }
    }
    __syncthreads();

    int lane = t & 63, w = t >> 6;
    int l15 = lane & 15, l4 = lane >> 4;
    const unsigned short* w1e = w1t + (size_t)e * HIDN * 256;
    const unsigned short* w2e = w2t + (size_t)e * 256 * HIDN;

    f32x4 yacc[4][4];
#pragma unroll
    for (int m = 0; m < 4; ++m)
#pragma unroll
        for (int nf = 0; nf < 4; ++nf) yacc[m][nf] = f32x4{0.f, 0.f, 0.f, 0.f};

    for (int hc = 0; hc < 8; ++hc) {
        // ---- phase A: H[0:64][hc*128 + w*32 .. +32) = Xs @ W1
        f32x4 hacc[4][2];
#pragma unroll
        for (int m = 0; m < 4; ++m)
#pragma unroll
            for (int nf = 0; nf < 2; ++nf) hacc[m][nf] = f32x4{0.f, 0.f, 0.f, 0.f};
#pragma unroll
        for (int nf = 0; nf < 2; ++nf) {
            int nA = hc * 128 + w * 32 + nf * 16 + l15;
#pragma unroll
            for (int ks = 0; ks < 8; ++ks) {
                bf16x8 bfrag = *(const bf16x8*)(w1e + (size_t)nA * 256 + ks * 32 + l4 * 8);
#pragma unroll
                for (int m = 0; m < 4; ++m) {
                    int r = m * 16 + l15;
                    int chunk = ks * 4 + l4;
                    bf16x8 afrag = *(const bf16x8*)((const char*)Xs + r * 512 + ((chunk ^ (r & 31)) << 4));
                    hacc[m][nf] = __builtin_amdgcn_mfma_f32_16x16x32_bf16(afrag, bfrag, hacc[m][nf], 0, 0, 0);
                }
            }
        }
        // ---- gelu (tanh approx) + paired b32 writes into Hs
        int odd = l15 & 1;
#pragma unroll
        for (int nf = 0; nf < 2; ++nf) {
            int col = w * 32 + nf * 16 + l15;
            float bb = b1[e * HIDN + hc * 128 + col];
            int colb = (col & ~1) * 2;
            int chunk0 = colb >> 4;
#pragma unroll
            for (int m = 0; m < 4; ++m) {
                float gl[4], ex[4];
#pragma unroll
                for (int j = 0; j < 4; ++j) {
                    float vv = hacc[m][nf][j] + bb;
                    float tt = vv * (1.0f + 0.044715f * vv * vv);
                    gl[j] = vv * __builtin_amdgcn_rcpf(1.0f + __builtin_amdgcn_exp2f(-2.3022100f * tt));
                }
#pragma unroll
                for (int j = 0; j < 4; ++j) ex[j] = __shfl_xor(gl[j], 1);
#pragma unroll
                for (int jj = 0; jj < 2; ++jj) {
                    int j = odd * 2 + jj;
                    int r = m * 16 + l4 * 4 + j;
                    unsigned lo = f2bf(odd ? ex[j] : gl[j]);
                    unsigned hi = f2bf(odd ? gl[j] : ex[j]);
                    *(unsigned*)((char*)Hs + r * 256 + (((chunk0 ^ (r & 15)) << 4) | (colb & 15))) =
                        lo | (hi << 16);
                }
            }
        }
        __syncthreads();
        // ---- phase B: Y[0:64][w*64 .. +64) += Hs @ W2 chunk
#pragma unroll
        for (int ks = 0; ks < 4; ++ks) {
            bf16x8 aH[4];
#pragma unroll
            for (int m = 0; m < 4; ++m) {
                int r = m * 16 + l15;
                int chunk = ks * 4 + l4;
                aH[m] = *(const bf16x8*)((const char*)Hs + r * 256 + ((chunk ^ (r & 15)) << 4));
            }
#pragma unroll
            for (int nf = 0; nf < 4; ++nf) {
                int ncol = w * 64 + nf * 16 + l15;
                bf16x8 bW = *(const bf16x8*)(w2e + (size_t)ncol * HIDN + hc * 128 + ks * 32 + l4 * 8);
#pragma unroll
                for (int m = 0; m < 4; ++m)
                    yacc[m][nf] = __builtin_amdgcn_mfma_f32_16x16x32_bf16(aH[m], bW, yacc[m][nf], 0, 0, 0);
            }
        }
        __syncthreads();
    }
#pragma unroll
    for (int nf = 0; nf < 4; ++nf) {
        int col = w * 64 + nf * 16 + l15;
        float bb2 = b2[e * 256 + col];
#pragma unroll
        for (int m = 0; m < 4; ++m)
#pragma unroll
            for (int j = 0; j < 4; ++j) {
                int r = row0 + m * 16 + l4 * 4 + j;
                Y[((size_t)e * BE + r) * 256 + col] = f2bf(yacc[m][nf][j] + bb2);
            }
    }
}

// Gather expert outputs (bf16), gate, add residual, write NCHW. One block per (n,y) row.
__global__ __launch_bounds__(256) void k_gather(const float* __restrict__ input,
                                                const unsigned short* __restrict__ Y,
                                                const int2* __restrict__ slots,
                                                const float2* __restrict__ gates,
                                                const float* __restrict__ ls,
                                                float* __restrict__ out) {
    __shared__ float acc[32][257];
    int t = threadIdx.x;
    int n = blockIdx.x >> 5, y = blockIdx.x & 31;

    {   // step 1: per-token gated contribution into LDS [token][c]
        int tl = t & 31, chunk = t >> 5;
        int tok = n * 1024 + y * 32 + tl;
        int2  sl = slots[tok];
        float2 gw = gates[tok];
        int c0 = chunk * 32;
#pragma unroll
        for (int i = 0; i < 4; ++i) {
            int c = c0 + i * 8;
            float v[8];
#pragma unroll
            for (int k = 0; k < 8; ++k) v[k] = 0.f;
            if (sl.x >= 0) {
                bf16x8 yv = *(const bf16x8*)(Y + (size_t)sl.x * 256 + c);
#pragma unroll
                for (int k = 0; k < 8; ++k) v[k] += gw.x * bf2f((unsigned short)yv[k]);
            }
            if (sl.y >= 0) {
                bf16x8 yv = *(const bf16x8*)(Y + (size_t)sl.y * 256 + c);
#pragma unroll
                for (int k = 0; k < 8; ++k) v[k] += gw.y * bf2f((unsigned short)yv[k]);
            }
#pragma unroll
            for (int k = 0; k < 8; ++k) acc[tl][c + k] = v[k];
        }
    }
    __syncthreads();
    {   // step 2: out[n,c,y,x] = input + ls[c] * acc[x][c], coalesced
        int x = t & 31, c8 = t >> 5;
        size_t base = (size_t)n * 256 * 1024 + (size_t)y * 32 + x;
#pragma unroll
        for (int p = 0; p < 32; ++p) {
            int c = p * 8 + c8;
            size_t id = base + (size_t)c * 1024;
            out[id] = input[id] + ls[c] * acc[x][c];
        }
    }
}

extern "C" void kernel_launch(void* const* d_in, const int* in_sizes, int n_in,
                              void* d_out, int out_size, void* d_ws, size_t ws_size,
                              hipStream_t stream) {
    const float* input = (const float*)d_in[0];
    const float* dwk   = (const float*)d_in[1];
    const float* dwb   = (const float*)d_in[2];
    const float* gamma = (const float*)d_in[3];
    const float* beta  = (const float*)d_in[4];
    const float* rw    = (const float*)d_in[5];
    const float* w1    = (const float*)d_in[6];
    const float* b1    = (const float*)d_in[7];
    const float* w2    = (const float*)d_in[8];
    const float* b2    = (const float*)d_in[9];
    const float* ls    = (const float*)d_in[10];

    char* ws = (char*)d_ws;
    // Y (40MiB bf16) aliases xc (32MiB f32): xc is dead before k_mlp writes Y.
    unsigned short* Yb   = (unsigned short*)ws;
    float*          xc   = (float*)ws;
    unsigned short* xln  = (unsigned short*)(ws + 83886080);   // 16MB
    unsigned short* w1t  = (unsigned short*)(ws + 100663296);  // 4MB
    unsigned short* w2t  = (unsigned short*)(ws + 104857600);  // 4MB
    int*            rtok = (int*)(ws + 109051904);             // 320KB
    int2*           slots = (int2*)(ws + 109379584);           // 256KB
    float2*         gates = (float2*)(ws + 109641728);         // 256KB
    int*            e01  = (int*)(ws + 109903872);             // 128KB
    int*            cnt  = (int*)(ws + 110035968);             // 8*64 ints

    k_init<<<1, NE * CNT_STRIDE, 0, stream>>>(cnt);
    k_conv<<<32768, 256, 0, stream>>>(input, dwk, dwb, xc);
    k_ln_router<<<8192, 256, 0, stream>>>(xc, gamma, beta, rw, xln, e01, gates);
    k_assign<<<128, 256, 0, stream>>>(e01, cnt, rtok, slots);
    k_transpose<<<dim3(32, 8, 8), 256, 0, stream>>>(w1, w1t, 256, 1024);  // w1t[e][h][c]
    k_transpose<<<dim3(8, 32, 8), 256, 0, stream>>>(w2, w2t, 1024, 256);  // w2t[e][c][h]
    k_mlp<<<1280, 256, 0, stream>>>(xln, w1t, w2t, b1, b2, cnt, rtok, Yb);
    k_gather<<<1024, 256, 0, stream>>>(input, Yb, slots, gates, ls, (float*)d_out);
}